// Round 6
// baseline (430.944 us; speedup 1.0000x reference)
//
#include <hip/hip_runtime.h>

#define BB 4
#define TT 1024
#define CCH 2048
#define HH 16
#define HDIM 128
#define NBLK 1024
#define MM (BB*TT)          // 4096
#define N1 (3*CCH)          // 6144
#define NQT 16              // T / 64

typedef _Float16 f16;
typedef _Float16 half8 __attribute__((ext_vector_type(8)));
typedef _Float16 half4 __attribute__((ext_vector_type(4)));
typedef float floatx4 __attribute__((ext_vector_type(4)));

// async global->LDS, 16B per lane. LDS dest = wave-uniform base + lane*16.
__device__ __forceinline__ void g2lds16(const void* g, void* l) {
    __builtin_amdgcn_global_load_lds((const __attribute__((address_space(1))) void*)g,
                                     (__attribute__((address_space(3))) void*)l, 16, 0, 0);
}

// ---- fused prep: z=0 transpose Wa -> WaT f16, z=1 Wp -> WpT, z=2 cvt x -> f16 ----
__global__ void k_prep(const float* __restrict__ Wa, const float* __restrict__ Wp,
                       const float* __restrict__ x,
                       f16* __restrict__ WaT, f16* __restrict__ WpT,
                       f16* __restrict__ x16) {
    int z = blockIdx.z;
    if (z == 2) {   // convert: MM*CCH/4 float4s
        int i = (blockIdx.y * 192 + blockIdx.x) * 256 + threadIdx.x + threadIdx.y * 32;
        if (i >= MM * CCH / 4) return;
        float4 v = ((const float4*)x)[i];
        union { ushort4 u; f16 h[4]; } o;
        o.h[0] = (f16)v.x; o.h[1] = (f16)v.y; o.h[2] = (f16)v.z; o.h[3] = (f16)v.w;
        ((ushort4*)x16)[i] = o.u;
        return;
    }
    const float* in = (z == 0) ? Wa : Wp;
    f16* out = (z == 0) ? WaT : WpT;
    int Cc = (z == 0) ? N1 : CCH;
    if (blockIdx.x * 32 >= Cc) return;
    __shared__ float tile[32][33];
    int c0 = blockIdx.x * 32, r0 = blockIdx.y * 32;
    int tx = threadIdx.x, ty = threadIdx.y;
#pragma unroll
    for (int k = 0; k < 4; k++) {
        int r = ty + k * 8;
        tile[r][tx] = in[(size_t)(r0 + r) * Cc + c0 + tx];
    }
    __syncthreads();
#pragma unroll
    for (int k = 0; k < 4; k++) {
        int r = ty + k * 8;
        out[(size_t)(c0 + r) * CCH + r0 + tx] = (f16)tile[tx][r];
    }
}

// ------- transpose f16 per-head [T][HD] -> [HD][T] (for V) -------
__global__ void k_trv(const f16* __restrict__ in, f16* __restrict__ out) {
    __shared__ f16 tile[32][34];
    int bh = blockIdx.z;
    int h0 = blockIdx.x * 32, t0 = blockIdx.y * 32;
    int tx = threadIdx.x, ty = threadIdx.y;
#pragma unroll
    for (int k = 0; k < 4; k++) {
        int t = ty + k * 8;
        tile[t][tx] = in[((size_t)bh * TT + t0 + t) * HDIM + h0 + tx];
    }
    __syncthreads();
#pragma unroll
    for (int k = 0; k < 4; k++) {
        int r = ty + k * 8;
        out[((size_t)bh * HDIM + h0 + r) * TT + t0 + tx] = tile[tx][r];
    }
}

// ---------------- global histogram over all B*T tokens ----------------
__global__ void k_hist(const int* __restrict__ tok, int* __restrict__ cnt) {
    int i = blockIdx.x * blockDim.x + threadIdx.x;
    if (i < MM) atomicAdd(cnt + tok[i], 1);
}

// ------- per-batch inclusive scan of 1/count; also padding bias -------
__global__ __launch_bounds__(1024) void k_scan(const int* __restrict__ tok,
                                               const int* __restrict__ cnt,
                                               const int* __restrict__ pm,
                                               float* __restrict__ tpos,
                                               float* __restrict__ pb) {
    __shared__ float s[TT];
    int b = blockIdx.x, t = threadIdx.x;
    s[t] = 1.0f / ((float)cnt[tok[b * TT + t]] + 1e-10f);
    __syncthreads();
    for (int off = 1; off < TT; off <<= 1) {
        float add = (t >= off) ? s[t - off] : 0.0f;
        __syncthreads();
        s[t] += add;
        __syncthreads();
    }
    tpos[b * TT + t] = s[t];
    pb[b * TT + t] = pm[b * TT + t] ? 0.0f : -1e30f;
}

// ------- rope table: tab[row*64+j] = (cos, sin) of tpos[row]*10000^(-j/64) -------
__global__ void k_rope(const float* __restrict__ tpos, float2* __restrict__ tab) {
    int i = blockIdx.x * 256 + threadIdx.x;     // MM*64 entries
    int row = i >> 6, j = i & 63;
    float f = tpos[row] * expf((float)j * -0.14391156929f);   // ln(10000)/64
    float sn, cn; sincosf(f, &sn, &cn);
    tab[i] = make_float2(cn, sn);
}

// ======== 256x128 software-pipelined GEMM, 4 waves x (128x64), BK=64, dbuf ========
// ROUND-6 CHANGE (LDS-port roofline fix): round 5 was LDS-read-bound —
//   8 waves x 10 b128/phase = 80KB ~963cy port vs 621cy MFMA -> 32% cap (measured).
//   Per-wave tile 128x32 -> 128x64 (acc[8][4]) at 4 waves (2x2): 48KB/phase
//   ~565cy port < 621cy MFMA. FLOP per LDS byte 25.6 -> 42.7. Block/grids/LDS/
//   swizzle/stage windows IDENTICAL to round 5 (passed, conflicts==0).
// B cols per wave: (nf&1)*64 + (nf>>1)*32 + wn*16 + l16 -> rope pairs (d,d+64)
//   are (nf even, nf odd) within one wave.
// Pipeline (per 2 K-tiles, 4 phases, 1 barrier each):
//   ph1: prefetch t.kk1(buf0); MFMA t.kk0; vmcnt(0)[t+1]; BAR
//   ph2: prefetch (t+1).kk0(buf1); STAGE t+2->buf0; MFMA t.kk1; BAR
//   ph3: prefetch (t+1).kk1(buf1); MFMA (t+1).kk0; vmcnt(0)[t+2]; BAR
//   ph4: prefetch (t+2).kk0(buf0); STAGE t+3->buf1; MFMA (t+1).kk1; BAR
// Rotation swizzle: LDS[r][c] = global chunk (c-r)&7 via pre-rotated source;
//   reads fetch chunk (quad+l16)&7 (ck0) and ^64 (ck1). Conflicts == 0 (r4 PMC).
#define BAR() __builtin_amdgcn_s_barrier()
#define RDA(S, buf, ck) do { _Pragma("unroll") for (int m_ = 0; m_ < 8; m_++) \
    S[m_] = *(const half8*)((const char*)As + ((buf) << 15) + aoffb + (m_ << 11) + (ck)); } while (0)
#define RDB(S, buf, ck) do { _Pragma("unroll") for (int n_ = 0; n_ < 4; n_++) \
    S[n_] = *(const half8*)((const char*)Bs + ((buf) << 14) + bofs[n_] + (ck)); } while (0)
#define STAGEA(t, lofs) do { _Pragma("unroll") for (int k_ = 0; k_ < 8; k_++) \
    g2lds16(Ab + (size_t)(k_ * 32) * 2048 + ((t) << 6) + srcr, \
            (char*)As + (lofs) + (w * 8 + k_ * 32) * 128); } while (0)
#define STAGEB(t, lofs) do { _Pragma("unroll") for (int k_ = 0; k_ < 4; k_++) \
    g2lds16(Bb + (size_t)(k_ * 32) * 2048 + ((t) << 6) + srcr, \
            (char*)Bs + (lofs) + (w * 8 + k_ * 32) * 128); } while (0)
#define MF16(SA, SB) do { _Pragma("unroll") for (int m_ = 0; m_ < 8; m_++) \
    _Pragma("unroll") for (int n_ = 0; n_ < 4; n_++) \
    acc[m_][n_] = __builtin_amdgcn_mfma_f32_16x16x32_f16(SA[m_], SB[n_], acc[m_][n_], 0, 0, 0); } while (0)

template <int MODE>   // 1: QKV fused rope epilogue (N=6144); 0: plain f32 C (N=2048)
__global__ __launch_bounds__(256, 1) void k_gemm8(const f16* __restrict__ A,
                                                  const f16* __restrict__ Bt,
                                                  float* __restrict__ Cp,
                                                  const float2* __restrict__ tab,
                                                  const float* __restrict__ cs,
                                                  f16* __restrict__ qr,
                                                  f16* __restrict__ kr,
                                                  f16* __restrict__ vsc) {
    const float SCALE = 0.08838834764831845f;   // 1/sqrt(128), folded into q
    const int NBN = MODE ? 48 : 16;
    const int NWG = MODE ? 768 : 256;
    const int CPX = NWG >> 3;
    __shared__ __align__(16) f16 As[2 * 16384];   // [buf][256][64], 64KB
    __shared__ __align__(16) f16 Bs[2 * 8192];    // [buf][128][64], 32KB

    int bid = blockIdx.x;
    int s = (bid & 7) * CPX + (bid >> 3);          // XCD swizzle (bijective: NWG%8==0)
    int bm = s / NBN, bn = s % NBN;

    int tid = threadIdx.x;
    int w = tid >> 6, lane = tid & 63, quad = lane >> 4, l16 = lane & 15;
    int wm = w >> 1, wn = w & 1;                   // 2 x 2 wave grid, 128x64 each

    const f16* Ab = A + (size_t)(bm << 8) * 2048;
    const f16* Bb = Bt + (size_t)(bn << 7) * 2048;

    // rotation-swizzle staging source: lane = (row rl, chunk cl); source chunk
    // (cl - row)&7 (row-block offsets are ==0 mod 8, so gl is row-invariant).
    int rl = lane >> 3, cl = lane & 7;
    int gl = (cl - rl) & 7;
    int srcr = (w * 8 + rl) * 2048 + gl * 8;

    // frag-read bases; read chunk (g + row)&7, row&7 == l16&7, g = kk*4 + quad.
    const int aoffb = (wm * 128 + l16) << 7;
    const int bc0 = wn * 16 + l16;                 // 0..31
    const int bofs[4] = { bc0 << 7, (bc0 + 64) << 7, (bc0 + 32) << 7, (bc0 + 96) << 7 };
    const int ck0 = ((quad + l16) & 7) << 4;
    const int ck1 = ck0 ^ 64;

    floatx4 acc[8][4];
#pragma unroll
    for (int i = 0; i < 8; i++)
#pragma unroll
        for (int j = 0; j < 4; j++) acc[i][j] = (floatx4){0.f, 0.f, 0.f, 0.f};

    half8 S0a[8], S1a[8];
    half8 S0b[4], S1b[4];

    // prologue: stage tile0 -> buf0 (12 loads/wave), tile1 -> buf1 (12)
    STAGEA(0, 0);      STAGEB(0, 0);
    STAGEA(1, 32768);  STAGEB(1, 16384);
    asm volatile("s_waitcnt vmcnt(12)" ::: "memory");  // tile0 landed
    BAR();
    RDA(S0a, 0, ck0); RDB(S0b, 0, ck0);                // tile0.kk0 -> S0

#pragma unroll 1
    for (int i = 0; i < 16; ++i) {
        const int t2 = 2 * i + 2, t3 = 2 * i + 3;
        // ph1: prefetch t.kk1 -> S1; compute t.kk0; wait stage(t+1); BAR
        RDA(S1a, 0, ck1); RDB(S1b, 0, ck1);
        __builtin_amdgcn_s_setprio(1); MF16(S0a, S0b); __builtin_amdgcn_s_setprio(0);
        asm volatile("s_waitcnt vmcnt(0)" ::: "memory");   // (t+1) landed
        BAR();
        // ph2: prefetch (t+1).kk0 -> S0; stage t+2 -> buf0; compute t.kk1; BAR
        RDA(S0a, 1, ck0); RDB(S0b, 1, ck0);
        if (t2 < 32) { STAGEA(t2, 0); STAGEB(t2, 0); }
        __builtin_amdgcn_s_setprio(1); MF16(S1a, S1b); __builtin_amdgcn_s_setprio(0);
        BAR();
        // ph3: prefetch (t+1).kk1 -> S1; compute (t+1).kk0; wait stage(t+2); BAR
        RDA(S1a, 1, ck1); RDB(S1b, 1, ck1);
        __builtin_amdgcn_s_setprio(1); MF16(S0a, S0b); __builtin_amdgcn_s_setprio(0);
        asm volatile("s_waitcnt vmcnt(0)" ::: "memory");   // (t+2) landed
        BAR();
        // ph4: prefetch (t+2).kk0 -> S0; stage t+3 -> buf1; compute (t+1).kk1; BAR
        RDA(S0a, 0, ck0); RDB(S0b, 0, ck0);                // stale on last iter: unused
        if (t3 < 32) { STAGEA(t3, 32768); STAGEB(t3, 16384); }
        __builtin_amdgcn_s_setprio(1); MF16(S1a, S1b); __builtin_amdgcn_s_setprio(0);
        BAR();
    }

    // ---- epilogue: rows = bm*256 + wm*128 + mf*16 + quad*4 + r
    //      cols = bn*128 + (nf&1)*64 + (nf>>1)*32 + wn*16 + l16
    if (MODE == 0) {
#pragma unroll
        for (int mf = 0; mf < 8; mf++)
#pragma unroll
            for (int nf = 0; nf < 4; nf++) {
                int col = (bn << 7) + ((nf & 1) << 6) + ((nf >> 1) << 5) + wn * 16 + l16;
#pragma unroll
                for (int r = 0; r < 4; r++) {
                    int row = (bm << 8) + wm * 128 + mf * 16 + (quad << 2) + r;
                    Cp[(size_t)row * CCH + col] = acc[mf][nf][r];
                }
            }
    } else {
        int type = bn >> 4;              // 0=q, 1=k, 2=v (16 blocks per 2048-col chunk)
        int h = bn & 15;                 // one head per block
        if (type < 2) {
            f16* outp = (type == 0) ? qr : kr;
#pragma unroll
            for (int mf = 0; mf < 8; mf++)
#pragma unroll
                for (int r = 0; r < 4; r++) {
                    int row = (bm << 8) + wm * 128 + mf * 16 + (quad << 2) + r;
#pragma unroll
                    for (int p = 0; p < 2; p++) {     // rope pairs: nf {0,1}, {2,3}
                        int d1 = p * 32 + wn * 16 + l16;   // 0..63
                        float2 tc = tab[row * 64 + d1];
                        float a1 = acc[mf][2 * p][r], a2 = acc[mf][2 * p + 1][r];
                        float o1 = a1 * tc.x - a2 * tc.y;
                        float o2 = a2 * tc.x + a1 * tc.y;
                        if (type == 0) {
                            if (d1 == 63) o2 = 1.0f;          // q[...,-1]=1 (before scale)
                            o1 *= SCALE; o2 *= SCALE;
                        } else {
                            if (d1 == 63) o2 = cs[row];       // k[...,-1]=cum_scores
                        }
                        size_t ob = ((size_t)((row >> 10) * HH + h) * TT + (row & 1023)) * HDIM + d1;
                        outp[ob] = (f16)o1;
                        outp[ob + 64] = (f16)o2;
                    }
                }
        } else {
#pragma unroll
            for (int mf = 0; mf < 8; mf++)
#pragma unroll
                for (int r = 0; r < 4; r++) {
                    int row = (bm << 8) + wm * 128 + mf * 16 + (quad << 2) + r;
                    float ve = __expf(cs[row]);
#pragma unroll
                    for (int nf = 0; nf < 4; nf++) {
                        int d = ((nf & 1) << 6) + ((nf >> 1) << 5) + wn * 16 + l16;
                        size_t ob = ((size_t)((row >> 10) * HH + h) * TT + (row & 1023)) * HDIM + d;
                        vsc[ob] = (f16)(acc[mf][nf][r] * ve);
                    }
                }
        }
    }
}

// ---------------- causal flash attention, S^T formulation ----------------
__global__ __launch_bounds__(256) void k_attn(const f16* __restrict__ qr,
                                              const f16* __restrict__ kr,
                                              const f16* __restrict__ vt,
                                              const float* __restrict__ pb,
                                              f16* __restrict__ y) {
    __shared__ __align__(16) f16 Ks[64 * 136];   // [kv][hd], pad 128->136
    __shared__ __align__(16) f16 Vs[128 * 72];   // [hd][kv], pad 64->72
    __shared__ float pbs[64];
    int p = blockIdx.x & (NQT / 2 - 1);
    int bh = blockIdx.x >> 3;
    int b = bh >> 4, h = bh & 15;
    int tid = threadIdx.x;
    int w = tid >> 6, lane = tid & 63, quad = lane >> 4, l16 = lane & 15;
#pragma unroll
    for (int pass = 0; pass < 2; pass++) {
        int qt = pass ? (NQT - 1 - p) : p;
        int q0 = qt << 6;
        int qg = q0 + w * 16 + l16;                  // this lane's q column
        const f16* Qp = qr + ((size_t)bh * TT + qg) * HDIM;
        half8 qf[4];                                  // B-op: Q[q=l16][hd=kc*32+quad*8+e]
#pragma unroll
        for (int kc = 0; kc < 4; kc++) qf[kc] = *(const half8*)&Qp[kc * 32 + (quad << 3)];
        floatx4 O[8];                                 // O^T[hd][q] C-frags
#pragma unroll
        for (int i = 0; i < 8; i++) O[i] = (floatx4){0.f, 0.f, 0.f, 0.f};
        float mx = -1e30f, ls = 0.f;
        for (int kt = 0; kt <= qt; kt++) {
            __syncthreads();
            const f16* Kb = kr + ((size_t)bh * TT + (kt << 6)) * HDIM;
            const f16* Vb = vt + (size_t)bh * HDIM * TT + (kt << 6);
#pragma unroll
            for (int i = 0; i < 4; i++) {
                int seg = tid + (i << 8);
                int krow = seg >> 4, kcol = (seg & 15) << 3;
                *(uint4*)&Ks[krow * 136 + kcol] = *(const uint4*)&Kb[(size_t)krow * HDIM + kcol];
                int vrow = seg >> 3, vcol = (seg & 7) << 3;
                *(uint4*)&Vs[vrow * 72 + vcol] = *(const uint4*)&Vb[(size_t)vrow * TT + vcol];
            }
            if (tid < 64) pbs[tid] = pb[b * TT + (kt << 6) + tid];
            __syncthreads();
            // S^T = K * Q^T : C-layout S^T[kv=quad*4+i][q=l16]
            floatx4 Sv[4];
#pragma unroll
            for (int mc = 0; mc < 4; mc++) Sv[mc] = (floatx4){0.f, 0.f, 0.f, 0.f};
#pragma unroll
            for (int kc = 0; kc < 4; kc++)
#pragma unroll
                for (int mc = 0; mc < 4; mc++) {
                    half8 kf = *(const half8*)&Ks[(mc * 16 + l16) * 136 + kc * 32 + (quad << 3)];
                    Sv[mc] = __builtin_amdgcn_mfma_f32_16x16x32_f16(kf, qf[kc], Sv[mc], 0, 0, 0);
                }
            // mask + bias + online softmax (per q column = per lane)
            float pv[4][4];
            float mnew = mx;
#pragma unroll
            for (int mc = 0; mc < 4; mc++) {
                float4 pbv = *(const float4*)&pbs[mc * 16 + (quad << 2)];
#pragma unroll
                for (int i = 0; i < 4; i++) {
                    int kv = (kt << 6) + mc * 16 + (quad << 2) + i;
                    float s = (kv <= qg) ? Sv[mc][i] + ((const float*)&pbv)[i] : -1e30f;
                    pv[mc][i] = s;
                    mnew = fmaxf(mnew, s);
                }
            }
            mnew = fmaxf(mnew, __shfl_xor(mnew, 16));
            mnew = fmaxf(mnew, __shfl_xor(mnew, 32));
            float al = __expf(mx - mnew);
            mx = mnew;
            float psum = 0.f;
#pragma unroll
            for (int mc = 0; mc < 4; mc++)
#pragma unroll
                for (int i = 0; i < 4; i++) {
                    float e = __expf(pv[mc][i] - mnew);
                    pv[mc][i] = e;
                    psum += e;
                }
            psum += __shfl_xor(psum, 16);
            psum += __shfl_xor(psum, 32);
            ls = ls * al + psum;
#pragma unroll
            for (int hm = 0; hm < 8; hm++)
#pragma unroll
                for (int i = 0; i < 4; i++) O[hm][i] *= al;
            // P^T as B-operand of 16x16x16 (k=quad*4+i == C rows). A = V^T.
            half4 pf[4];
#pragma unroll
            for (int mc = 0; mc < 4; mc++) {
                pf[mc][0] = (f16)pv[mc][0]; pf[mc][1] = (f16)pv[mc][1];
                pf[mc][2] = (f16)pv[mc][2]; pf[mc][3] = (f16)pv[mc][3];
            }
#pragma unroll
            for (int mc = 0; mc < 4; mc++)
#pragma unroll
                for (int hm = 0; hm < 8; hm++) {
                    half4 vf = *(const half4*)&Vs[(hm * 16 + l16) * 72 + mc * 16 + (quad << 2)];
                    O[hm] = __builtin_amdgcn_mfma_f32_16x16x16f16(vf, pf[mc], O[hm], 0, 0, 0);
                }
        }
        float inv = 1.0f / ls;
#pragma unroll
        for (int hm = 0; hm < 8; hm++) {
            half4 ov;
#pragma unroll
            for (int i = 0; i < 4; i++) ov[i] = (f16)(O[hm][i] * inv);
            *(half4*)&y[((size_t)b * TT + qg) * CCH + h * HDIM + hm * 16 + (quad << 2)] = ov;
        }
        __syncthreads();   // protect LDS before next pass restages
    }
}

extern "C" void kernel_launch(void* const* d_in, const int* in_sizes, int n_in,
                              void* d_out, int out_size, void* d_ws, size_t ws_size,
                              hipStream_t stream) {
    const float* x   = (const float*)d_in[0];
    const float* cs  = (const float*)d_in[1];
    const int*   tok = (const int*)d_in[2];
    const int*   pm  = (const int*)d_in[3];
    const float* Wa  = (const float*)d_in[4];
    const float* Wp  = (const float*)d_in[5];
    float* out = (float*)d_out;
    char* ws = (char*)d_ws;

    f16* x16 = (f16*)(ws + 0);             // 16 MB ; reused as y after GEMM1
    f16* WaT = (f16*)(ws + 16777216);      // 24 MB
    f16* vt  = (f16*)(ws + 41943040);      // 16 MB   [bh][hd][t]
    f16* WpT = (f16*)(ws + 58720256);      //  8 MB
    float2* tab = (float2*)(ws + 67108864);// 2 MB rope table (gap before qr)
    f16* qr  = (f16*)(ws + 92274688);      // 16 MB
    f16* kr  = (f16*)(ws + 109051904);     // 16 MB
    f16* vsc = (f16*)(ws + 125829120);     // 16 MB
    int*   cnt  = (int*)(ws + 142606336);  // 4 KB
    float* tpos = (float*)(ws + 142610432);// 16 KB
    float* pb   = (float*)(ws + 142626816);// 16 KB
    f16* y   = x16;

    hipMemsetAsync(cnt, 0, NBLK * sizeof(int), stream);
    k_hist<<<MM / 256, 256, 0, stream>>>(tok, cnt);
    k_scan<<<BB, TT, 0, stream>>>(tok, cnt, pm, tpos, pb);
    k_rope<<<MM * 64 / 256, 256, 0, stream>>>(tpos, tab);
    k_prep<<<dim3(N1 / 32, CCH / 32, 3), dim3(32, 8), 0, stream>>>(Wa, Wp, x, WaT, WpT, x16);
    k_gemm8<1><<<768, 256, 0, stream>>>(x16, WaT, nullptr, tab, cs, qr, kr, vsc);
    k_trv<<<dim3(4, 32, BB * HH), dim3(32, 8), 0, stream>>>(vsc, vt);
    k_attn<<<BB * HH * (NQT / 2), 256, 0, stream>>>(qr, kr, vt, pb, y);
    k_gemm8<0><<<256, 256, 0, stream>>>(y, WpT, out, nullptr, nullptr, nullptr, nullptr, nullptr);
}

// Round 7
// 386.388 us; speedup vs baseline: 1.1153x; 1.1153x over previous
//
#include <hip/hip_runtime.h>

#define BB 4
#define TT 1024
#define CCH 2048
#define HH 16
#define HDIM 128
#define NBLK 1024
#define MM (BB*TT)          // 4096
#define N1 (3*CCH)          // 6144
#define NQT 16              // T / 64

typedef _Float16 f16;
typedef _Float16 half8 __attribute__((ext_vector_type(8)));
typedef _Float16 half4 __attribute__((ext_vector_type(4)));
typedef float floatx4 __attribute__((ext_vector_type(4)));

// async global->LDS, 16B per lane. LDS dest = wave-uniform base + lane*16.
__device__ __forceinline__ void g2lds16(const void* g, void* l) {
    __builtin_amdgcn_global_load_lds((const __attribute__((address_space(1))) void*)g,
                                     (__attribute__((address_space(3))) void*)l, 16, 0, 0);
}

// ---- fused prep: z=0 transpose Wa -> WaT f16, z=1 Wp -> WpT, z=2 cvt x -> f16 ----
__global__ void k_prep(const float* __restrict__ Wa, const float* __restrict__ Wp,
                       const float* __restrict__ x,
                       f16* __restrict__ WaT, f16* __restrict__ WpT,
                       f16* __restrict__ x16) {
    int z = blockIdx.z;
    if (z == 2) {   // convert: MM*CCH/4 float4s
        int i = (blockIdx.y * 192 + blockIdx.x) * 256 + threadIdx.x + threadIdx.y * 32;
        if (i >= MM * CCH / 4) return;
        float4 v = ((const float4*)x)[i];
        union { ushort4 u; f16 h[4]; } o;
        o.h[0] = (f16)v.x; o.h[1] = (f16)v.y; o.h[2] = (f16)v.z; o.h[3] = (f16)v.w;
        ((ushort4*)x16)[i] = o.u;
        return;
    }
    const float* in = (z == 0) ? Wa : Wp;
    f16* out = (z == 0) ? WaT : WpT;
    int Cc = (z == 0) ? N1 : CCH;
    if (blockIdx.x * 32 >= Cc) return;
    __shared__ float tile[32][33];
    int c0 = blockIdx.x * 32, r0 = blockIdx.y * 32;
    int tx = threadIdx.x, ty = threadIdx.y;
#pragma unroll
    for (int k = 0; k < 4; k++) {
        int r = ty + k * 8;
        tile[r][tx] = in[(size_t)(r0 + r) * Cc + c0 + tx];
    }
    __syncthreads();
#pragma unroll
    for (int k = 0; k < 4; k++) {
        int r = ty + k * 8;
        out[(size_t)(c0 + r) * CCH + r0 + tx] = (f16)tile[tx][r];
    }
}

// ------- transpose f16 per-head [T][HD] -> [HD][T] (for V) -------
__global__ void k_trv(const f16* __restrict__ in, f16* __restrict__ out) {
    __shared__ f16 tile[32][34];
    int bh = blockIdx.z;
    int h0 = blockIdx.x * 32, t0 = blockIdx.y * 32;
    int tx = threadIdx.x, ty = threadIdx.y;
#pragma unroll
    for (int k = 0; k < 4; k++) {
        int t = ty + k * 8;
        tile[t][tx] = in[((size_t)bh * TT + t0 + t) * HDIM + h0 + tx];
    }
    __syncthreads();
#pragma unroll
    for (int k = 0; k < 4; k++) {
        int r = ty + k * 8;
        out[((size_t)bh * HDIM + h0 + r) * TT + t0 + tx] = tile[tx][r];
    }
}

// ---------------- global histogram over all B*T tokens ----------------
__global__ void k_hist(const int* __restrict__ tok, int* __restrict__ cnt) {
    int i = blockIdx.x * blockDim.x + threadIdx.x;
    if (i < MM) atomicAdd(cnt + tok[i], 1);
}

// ------- per-batch inclusive scan of 1/count; also padding bias -------
__global__ __launch_bounds__(1024) void k_scan(const int* __restrict__ tok,
                                               const int* __restrict__ cnt,
                                               const int* __restrict__ pm,
                                               float* __restrict__ tpos,
                                               float* __restrict__ pb) {
    __shared__ float s[TT];
    int b = blockIdx.x, t = threadIdx.x;
    s[t] = 1.0f / ((float)cnt[tok[b * TT + t]] + 1e-10f);
    __syncthreads();
    for (int off = 1; off < TT; off <<= 1) {
        float add = (t >= off) ? s[t - off] : 0.0f;
        __syncthreads();
        s[t] += add;
        __syncthreads();
    }
    tpos[b * TT + t] = s[t];
    pb[b * TT + t] = pm[b * TT + t] ? 0.0f : -1e30f;
}

// ------- rope table: tab[row*64+j] = (cos, sin) of tpos[row]*10000^(-j/64) -------
__global__ void k_rope(const float* __restrict__ tpos, float2* __restrict__ tab) {
    int i = blockIdx.x * 256 + threadIdx.x;     // MM*64 entries
    int row = i >> 6, j = i & 63;
    float f = tpos[row] * expf((float)j * -0.14391156929f);   // ln(10000)/64
    float sn, cn; sincosf(f, &sn, &cn);
    tab[i] = make_float2(cn, sn);
}

// ===== 256x128 GEMM, 8 waves x (128x32), BK=64, TRIPLE-buffered counted-vmcnt =====
// ROUND-7: geometry reverted to round 5 (best passing: 135us, conflicts==0,
//   2 waves/SIMD). ONE change: dbuf+vmcnt(0) -> 3-buf+vmcnt(6) (T4). Round 5
//   drained all in-flight loads one phase (~600cy) after issue — under the
//   ~900cy HBM latency — twice per 2 K-tiles; m218: drain-0 ≈ unpipelined.
//   Now: stage tile t+2 while computing t; wait vmcnt(6) (retires ONLY t+1's
//   6 loads/wave) -> 2 phases (~1900cy) of flight. vmcnt(0) only at t>=30.
// Per tile t (2 phases, 1 barrier each, buffers rotate cur<-nxt<-stg):
//   ph1: RD S1<-cur.kk1; STAGE t+2->stg; MFMA S0 (t.kk0); vmcnt(6); BAR
//   ph2: RD S0<-nxt.kk0; MFMA S1 (t.kk1); BAR
// WAR safety: stg == buf last read at t-1 ph1, lgkm-waited before t-1 ph2's
//   MFMA, and stage issues after t-1 ph2's BAR. Rotation swizzle verbatim.
#define BAR() __builtin_amdgcn_s_barrier()
#define RDA(S, base, ck) do { _Pragma("unroll") for (int m_ = 0; m_ < 8; m_++) \
    S[m_] = *(const half8*)((base) + aoffb + (m_ << 11) + (ck)); } while (0)
#define RDB(S, base, ck) do { _Pragma("unroll") for (int n_ = 0; n_ < 2; n_++) \
    S[n_] = *(const half8*)((base) + boffb + (n_ << 13) + (ck)); } while (0)
#define STAGEA(t, base) do { _Pragma("unroll") for (int k_ = 0; k_ < 4; k_++) \
    g2lds16(Ab + (size_t)(k_ * 64) * 2048 + ((t) << 6) + srcr, \
            (base) + (w * 8 + k_ * 64) * 128); } while (0)
#define STAGEB(t, base) do { _Pragma("unroll") for (int k_ = 0; k_ < 2; k_++) \
    g2lds16(Bb + (size_t)(k_ * 64) * 2048 + ((t) << 6) + srcr, \
            (base) + (w * 8 + k_ * 64) * 128); } while (0)
#define MF16(SA, SB) do { _Pragma("unroll") for (int m_ = 0; m_ < 8; m_++) \
    _Pragma("unroll") for (int n_ = 0; n_ < 2; n_++) \
    acc[m_][n_] = __builtin_amdgcn_mfma_f32_16x16x32_f16(SA[m_], SB[n_], acc[m_][n_], 0, 0, 0); } while (0)

template <int MODE>   // 1: QKV fused rope epilogue (N=6144); 0: plain f32 C (N=2048)
__global__ __launch_bounds__(512, 2) void k_gemm8(const f16* __restrict__ A,
                                                  const f16* __restrict__ Bt,
                                                  float* __restrict__ Cp,
                                                  const float2* __restrict__ tab,
                                                  const float* __restrict__ cs,
                                                  f16* __restrict__ qr,
                                                  f16* __restrict__ kr,
                                                  f16* __restrict__ vsc) {
    const float SCALE = 0.08838834764831845f;   // 1/sqrt(128), folded into q
    const int NBN = MODE ? 48 : 16;
    const int NWG = MODE ? 768 : 256;
    const int CPX = NWG >> 3;
    __shared__ __align__(16) f16 As[3 * 16384];   // [3 buf][256][64], 96KB
    __shared__ __align__(16) f16 Bs[3 * 8192];    // [3 buf][128][64], 48KB

    int bid = blockIdx.x;
    int s = (bid & 7) * CPX + (bid >> 3);          // XCD swizzle (bijective: NWG%8==0)
    int bm = s / NBN, bn = s % NBN;

    int tid = threadIdx.x;
    int w = tid >> 6, lane = tid & 63, quad = lane >> 4, l16 = lane & 15;
    int wm = w >> 2, wn = w & 3;                   // 2 x 4 wave grid, 128x32 each

    const f16* Ab = A + (size_t)(bm << 8) * 2048;
    const f16* Bb = Bt + (size_t)(bn << 7) * 2048;

    // rotation-swizzle staging source: lane = (row rl, chunk cl); source chunk
    // (cl - row)&7 (row-block offsets are ==0 mod 8, so gl is row-invariant).
    int rl = lane >> 3, cl = lane & 7;
    int gl = (cl - rl) & 7;
    int srcr = (w * 8 + rl) * 2048 + gl * 8;

    // frag-read bases; read chunk (g + row)&7, row&7 == l16&7, g = kk*4 + quad.
    const int aoffb = (wm * 128 + l16) << 7;
    const int boffb = (wn * 16 + l16) << 7;
    const int ck0 = ((quad + l16) & 7) << 4;
    const int ck1 = ck0 ^ 64;

    floatx4 acc[8][2];
#pragma unroll
    for (int i = 0; i < 8; i++)
#pragma unroll
        for (int j = 0; j < 2; j++) acc[i][j] = (floatx4){0.f, 0.f, 0.f, 0.f};

    half8 S0a[8], S1a[8];
    half8 S0b[2], S1b[2];

    char* a0 = (char*)As; char* a1 = a0 + 32768; char* a2 = a0 + 65536;
    char* b0 = (char*)Bs; char* b1 = b0 + 16384; char* b2 = b0 + 32768;

    // prologue: stage t0 -> buf0 (6 loads/wave), t1 -> buf1 (6)
    STAGEA(0, a0); STAGEB(0, b0);
    STAGEA(1, a1); STAGEB(1, b1);
    asm volatile("s_waitcnt vmcnt(6)" ::: "memory");   // t0 landed (t1 in flight)
    BAR();
    RDA(S0a, a0, ck0); RDB(S0b, b0, ck0);              // t0.kk0 -> S0

#pragma unroll 1
    for (int t = 0; t < 32; ++t) {
        // ph1: RD S1 <- cur.kk1; stage t+2 -> stg; MFMA t.kk0; counted vmcnt; BAR
        RDA(S1a, a0, ck1); RDB(S1b, b0, ck1);
        if (t + 2 < 32) { STAGEA(t + 2, a2); STAGEB(t + 2, b2); }
        __builtin_amdgcn_s_setprio(1); MF16(S0a, S0b); __builtin_amdgcn_s_setprio(0);
        if (t < 30) { asm volatile("s_waitcnt vmcnt(6)" ::: "memory"); }
        else        { asm volatile("s_waitcnt vmcnt(0)" ::: "memory"); }
        BAR();
        // ph2: RD S0 <- nxt.kk0; MFMA t.kk1; BAR
        if (t < 31) { RDA(S0a, a1, ck0); RDB(S0b, b1, ck0); }
        __builtin_amdgcn_s_setprio(1); MF16(S1a, S1b); __builtin_amdgcn_s_setprio(0);
        BAR();
        // rotate buffers: cur <- nxt <- stg <- cur
        char* ta = a0; a0 = a1; a1 = a2; a2 = ta;
        char* tb = b0; b0 = b1; b1 = b2; b2 = tb;
    }

    // ---- epilogue: rows = bm*256 + wm*128 + mf*16 + quad*4 + r
    //      cols = bn*128 + wn*16 + nf*64 + l16   (nf pairs are d, d+64)
    if (MODE == 0) {
#pragma unroll
        for (int mf = 0; mf < 8; mf++)
#pragma unroll
            for (int nf = 0; nf < 2; nf++) {
                int col = (bn << 7) + wn * 16 + nf * 64 + l16;
#pragma unroll
                for (int r = 0; r < 4; r++) {
                    int row = (bm << 8) + wm * 128 + mf * 16 + (quad << 2) + r;
                    Cp[(size_t)row * CCH + col] = acc[mf][nf][r];
                }
            }
    } else {
        int type = bn >> 4;              // 0=q, 1=k, 2=v (16 blocks per 2048-col chunk)
        int h = bn & 15;                 // one head per block
        int d1 = wn * 16 + l16;          // 0..63 (low half of head dim)
        if (type < 2) {
            f16* outp = (type == 0) ? qr : kr;
#pragma unroll
            for (int mf = 0; mf < 8; mf++)
#pragma unroll
                for (int r = 0; r < 4; r++) {
                    int row = (bm << 8) + wm * 128 + mf * 16 + (quad << 2) + r;
                    float2 tc = tab[row * 64 + d1];
                    float a1v = acc[mf][0][r], a2v = acc[mf][1][r];
                    float o1 = a1v * tc.x - a2v * tc.y;
                    float o2 = a2v * tc.x + a1v * tc.y;
                    if (type == 0) {
                        if (d1 == 63) o2 = 1.0f;          // q[...,-1]=1 (before scale)
                        o1 *= SCALE; o2 *= SCALE;
                    } else {
                        if (d1 == 63) o2 = cs[row];       // k[...,-1]=cum_scores
                    }
                    size_t ob = ((size_t)((row >> 10) * HH + h) * TT + (row & 1023)) * HDIM + d1;
                    outp[ob] = (f16)o1;
                    outp[ob + 64] = (f16)o2;
                }
        } else {
#pragma unroll
            for (int mf = 0; mf < 8; mf++)
#pragma unroll
                for (int r = 0; r < 4; r++) {
                    int row = (bm << 8) + wm * 128 + mf * 16 + (quad << 2) + r;
                    float ve = __expf(cs[row]);
                    size_t ob = ((size_t)((row >> 10) * HH + h) * TT + (row & 1023)) * HDIM + d1;
                    vsc[ob]      = (f16)(acc[mf][0][r] * ve);
                    vsc[ob + 64] = (f16)(acc[mf][1][r] * ve);
                }
        }
    }
}

// ---------------- causal flash attention, S^T formulation ----------------
__global__ __launch_bounds__(256) void k_attn(const f16* __restrict__ qr,
                                              const f16* __restrict__ kr,
                                              const f16* __restrict__ vt,
                                              const float* __restrict__ pb,
                                              f16* __restrict__ y) {
    __shared__ __align__(16) f16 Ks[64 * 136];   // [kv][hd], pad 128->136
    __shared__ __align__(16) f16 Vs[128 * 72];   // [hd][kv], pad 64->72
    __shared__ float pbs[64];
    int p = blockIdx.x & (NQT / 2 - 1);
    int bh = blockIdx.x >> 3;
    int b = bh >> 4, h = bh & 15;
    int tid = threadIdx.x;
    int w = tid >> 6, lane = tid & 63, quad = lane >> 4, l16 = lane & 15;
#pragma unroll
    for (int pass = 0; pass < 2; pass++) {
        int qt = pass ? (NQT - 1 - p) : p;
        int q0 = qt << 6;
        int qg = q0 + w * 16 + l16;                  // this lane's q column
        const f16* Qp = qr + ((size_t)bh * TT + qg) * HDIM;
        half8 qf[4];                                  // B-op: Q[q=l16][hd=kc*32+quad*8+e]
#pragma unroll
        for (int kc = 0; kc < 4; kc++) qf[kc] = *(const half8*)&Qp[kc * 32 + (quad << 3)];
        floatx4 O[8];                                 // O^T[hd][q] C-frags
#pragma unroll
        for (int i = 0; i < 8; i++) O[i] = (floatx4){0.f, 0.f, 0.f, 0.f};
        float mx = -1e30f, ls = 0.f;
        for (int kt = 0; kt <= qt; kt++) {
            __syncthreads();
            const f16* Kb = kr + ((size_t)bh * TT + (kt << 6)) * HDIM;
            const f16* Vb = vt + (size_t)bh * HDIM * TT + (kt << 6);
#pragma unroll
            for (int i = 0; i < 4; i++) {
                int seg = tid + (i << 8);
                int krow = seg >> 4, kcol = (seg & 15) << 3;
                *(uint4*)&Ks[krow * 136 + kcol] = *(const uint4*)&Kb[(size_t)krow * HDIM + kcol];
                int vrow = seg >> 3, vcol = (seg & 7) << 3;
                *(uint4*)&Vs[vrow * 72 + vcol] = *(const uint4*)&Vb[(size_t)vrow * TT + vcol];
            }
            if (tid < 64) pbs[tid] = pb[b * TT + (kt << 6) + tid];
            __syncthreads();
            // S^T = K * Q^T : C-layout S^T[kv=quad*4+i][q=l16]
            floatx4 Sv[4];
#pragma unroll
            for (int mc = 0; mc < 4; mc++) Sv[mc] = (floatx4){0.f, 0.f, 0.f, 0.f};
#pragma unroll
            for (int kc = 0; kc < 4; kc++)
#pragma unroll
                for (int mc = 0; mc < 4; mc++) {
                    half8 kf = *(const half8*)&Ks[(mc * 16 + l16) * 136 + kc * 32 + (quad << 3)];
                    Sv[mc] = __builtin_amdgcn_mfma_f32_16x16x32_f16(kf, qf[kc], Sv[mc], 0, 0, 0);
                }
            // mask + bias + online softmax (per q column = per lane)
            float pv[4][4];
            float mnew = mx;
#pragma unroll
            for (int mc = 0; mc < 4; mc++) {
                float4 pbv = *(const float4*)&pbs[mc * 16 + (quad << 2)];
#pragma unroll
                for (int i = 0; i < 4; i++) {
                    int kv = (kt << 6) + mc * 16 + (quad << 2) + i;
                    float s = (kv <= qg) ? Sv[mc][i] + ((const float*)&pbv)[i] : -1e30f;
                    pv[mc][i] = s;
                    mnew = fmaxf(mnew, s);
                }
            }
            mnew = fmaxf(mnew, __shfl_xor(mnew, 16));
            mnew = fmaxf(mnew, __shfl_xor(mnew, 32));
            float al = __expf(mx - mnew);
            mx = mnew;
            float psum = 0.f;
#pragma unroll
            for (int mc = 0; mc < 4; mc++)
#pragma unroll
                for (int i = 0; i < 4; i++) {
                    float e = __expf(pv[mc][i] - mnew);
                    pv[mc][i] = e;
                    psum += e;
                }
            psum += __shfl_xor(psum, 16);
            psum += __shfl_xor(psum, 32);
            ls = ls * al + psum;
#pragma unroll
            for (int hm = 0; hm < 8; hm++)
#pragma unroll
                for (int i = 0; i < 4; i++) O[hm][i] *= al;
            // P^T as B-operand of 16x16x16 (k=quad*4+i == C rows). A = V^T.
            half4 pf[4];
#pragma unroll
            for (int mc = 0; mc < 4; mc++) {
                pf[mc][0] = (f16)pv[mc][0]; pf[mc][1] = (f16)pv[mc][1];
                pf[mc][2] = (f16)pv[mc][2]; pf[mc][3] = (f16)pv[mc][3];
            }
#pragma unroll
            for (int mc = 0; mc < 4; mc++)
#pragma unroll
                for (int hm = 0; hm < 8; hm++) {
                    half4 vf = *(const half4*)&Vs[(hm * 16 + l16) * 72 + mc * 16 + (quad << 2)];
                    O[hm] = __builtin_amdgcn_mfma_f32_16x16x16f16(vf, pf[mc], O[hm], 0, 0, 0);
                }
        }
        float inv = 1.0f / ls;
#pragma unroll
        for (int hm = 0; hm < 8; hm++) {
            half4 ov;
#pragma unroll
            for (int i = 0; i < 4; i++) ov[i] = (f16)(O[hm][i] * inv);
            *(half4*)&y[((size_t)b * TT + qg) * CCH + h * HDIM + hm * 16 + (quad << 2)] = ov;
        }
        __syncthreads();   // protect LDS before next pass restages
    }
}

extern "C" void kernel_launch(void* const* d_in, const int* in_sizes, int n_in,
                              void* d_out, int out_size, void* d_ws, size_t ws_size,
                              hipStream_t stream) {
    const float* x   = (const float*)d_in[0];
    const float* cs  = (const float*)d_in[1];
    const int*   tok = (const int*)d_in[2];
    const int*   pm  = (const int*)d_in[3];
    const float* Wa  = (const float*)d_in[4];
    const float* Wp  = (const float*)d_in[5];
    float* out = (float*)d_out;
    char* ws = (char*)d_ws;

    f16* x16 = (f16*)(ws + 0);             // 16 MB ; reused as y after GEMM1
    f16* WaT = (f16*)(ws + 16777216);      // 24 MB
    f16* vt  = (f16*)(ws + 41943040);      // 16 MB   [bh][hd][t]
    f16* WpT = (f16*)(ws + 58720256);      //  8 MB
    float2* tab = (float2*)(ws + 67108864);// 2 MB rope table (gap before qr)
    f16* qr  = (f16*)(ws + 92274688);      // 16 MB
    f16* kr  = (f16*)(ws + 109051904);     // 16 MB
    f16* vsc = (f16*)(ws + 125829120);     // 16 MB
    int*   cnt  = (int*)(ws + 142606336);  // 4 KB
    float* tpos = (float*)(ws + 142610432);// 16 KB
    float* pb   = (float*)(ws + 142626816);// 16 KB
    f16* y   = x16;

    hipMemsetAsync(cnt, 0, NBLK * sizeof(int), stream);
    k_hist<<<MM / 256, 256, 0, stream>>>(tok, cnt);
    k_scan<<<BB, TT, 0, stream>>>(tok, cnt, pm, tpos, pb);
    k_rope<<<MM * 64 / 256, 256, 0, stream>>>(tpos, tab);
    k_prep<<<dim3(N1 / 32, CCH / 32, 3), dim3(32, 8), 0, stream>>>(Wa, Wp, x, WaT, WpT, x16);
    k_gemm8<1><<<768, 512, 0, stream>>>(x16, WaT, nullptr, tab, cs, qr, kr, vsc);
    k_trv<<<dim3(4, 32, BB * HH), dim3(32, 8), 0, stream>>>(vsc, vt);
    k_attn<<<BB * HH * (NQT / 2), 256, 0, stream>>>(qr, kr, vt, pb, y);
    k_gemm8<0><<<256, 512, 0, stream>>>(y, WpT, out, nullptr, nullptr, nullptr, nullptr, nullptr);
}